// Round 5
// baseline (1677.551 us; speedup 1.0000x reference)
//
#include <hip/hip_runtime.h>
#include <hip/hip_fp16.h>
#include <hip/hip_cooperative_groups.h>

namespace cg = cooperative_groups;

// EMD approx-match (auction) + match_cost. The [B,N,M] match matrix is never
// materialized; O(B*N) state in d_ws. Per level l: B pass (col clip) then CA
// pass (cost + remainL update + next rowscale, sharing d2). Level 9 (lvl=0)
// specialized algebraically.
//
// R5: cooperative single-kernel with PERSISTENT TILES (any grid size works),
// grid sized by the runtime's own occupancy calculator so the cooperative
// launch cannot be rejected (R4's silent failure). LDS cut to ~17 KB via
// 2-chunk staging so even a 64-KB occupancy model grants >=3 blocks/CU.
// Non-cooperative 21-kernel fallback (identical device code) if the coop
// attribute is absent.

#define BATCH 8
#define NPTS 2048
#define MPTS 2048
#define BLOCK 256
#define ROWS 16
#define CHUNK 1024
#define NTILE (BATCH * (NPTS / ROWS))  // 1024
#define LOG2E 1.44269504088896340736f

struct SmemT {
  float4 sP[CHUNK];     // 16 KB staging (half the cloud per chunk)
  float sRedS[ROWS * 4];
  float sRedC[ROWS * 4];
  float sRedR[ROWS * 4];
  float sCost[ROWS];
  float sW[4];
};

// ---------------------------------------------------------------------------
// A0: rowscale = 1/(sum_m exp(lvl0*d2) + 1e-9)  (remainL=remainR=1). Row pass.
__device__ __forceinline__ void dev_A0(int tile, int tid, const float* xyz1,
                                       const float* xyz2, float* rowscale,
                                       SmemT& sm) {
  const int b = tile >> 7;
  const int t0 = (tile & 127) * ROWS;
  const int wave = tid >> 6, lane = tid & 63;
  const int phase = lane >> 1, rg = lane & 1;
  const int r0 = t0 + rg * 8;
  const float L2 = -16384.0f * LOG2E;
  float x1[8], y1[8], z1[8], acc[8];
#pragma unroll
  for (int j = 0; j < 8; ++j) {
    const float* p = xyz1 + ((size_t)b * NPTS + r0 + j) * 3;
    x1[j] = p[0]; y1[j] = p[1]; z1[j] = p[2]; acc[j] = 0.0f;
  }
  for (int ch = 0; ch < 2; ++ch) {
    __syncthreads();
    for (int m = tid; m < CHUNK; m += BLOCK) {
      const float* p = xyz2 + ((size_t)b * MPTS + ch * CHUNK + m) * 3;
      sm.sP[m] = make_float4(p[0], p[1], p[2], 0.0f);
    }
    __syncthreads();
    const int mb = wave * 256 + phase;
#pragma unroll
    for (int it = 0; it < 8; ++it) {
      float4 v = sm.sP[mb + it * 32];
#pragma unroll
      for (int j = 0; j < 8; ++j) {
        float dx = x1[j] - v.x, dy = y1[j] - v.y, dz = z1[j] - v.z;
        float d2 = __builtin_fmaf(dx, dx, __builtin_fmaf(dy, dy, dz * dz));
        acc[j] += __builtin_amdgcn_exp2f(L2 * d2);
      }
    }
  }
#pragma unroll
  for (int j = 0; j < 8; ++j) {
    acc[j] += __shfl_xor(acc[j], 2, 64);
    acc[j] += __shfl_xor(acc[j], 4, 64);
    acc[j] += __shfl_xor(acc[j], 8, 64);
    acc[j] += __shfl_xor(acc[j], 16, 64);
    acc[j] += __shfl_xor(acc[j], 32, 64);
  }
  if (lane < 2) {
#pragma unroll
    for (int j = 0; j < 8; ++j) sm.sRedS[(rg * 8 + j) * 4 + wave] = acc[j];
  }
  __syncthreads();
  if (tid < ROWS) {
    float s = sm.sRedS[tid * 4] + sm.sRedS[tid * 4 + 1] + sm.sRedS[tid * 4 + 2] +
              sm.sRedS[tid * 4 + 3];
    rowscale[(size_t)b * NPTS + t0 + tid] = 1.0f / (s + 1e-9f);
  }
}

// ---------------------------------------------------------------------------
// B(l): col pass. t1 = sum_n exp(lvl*d2)*rs[n]; colsum = rr*t1;
// cs = min(rr/(colsum+1e-9),1); colcoef = rr*cs; remainR = max(rr-colsum*cs,0)
__device__ __forceinline__ void dev_B(int l, int tile, int tid,
                                      const float* xyz1, const float* xyz2,
                                      const float* rowscale, float* remainR,
                                      float* colcoef, SmemT& sm) {
  const int b = tile >> 7;
  const int t0 = (tile & 127) * ROWS;
  const int wave = tid >> 6, lane = tid & 63;
  const int phase = lane >> 1, rg = lane & 1;
  const int c0 = t0 + rg * 8;
  const float L2C = -__builtin_amdgcn_exp2f((float)(14 - 2 * l)) * LOG2E;
  float x2[8], y2[8], z2[8], acc[8];
#pragma unroll
  for (int j = 0; j < 8; ++j) {
    const float* p = xyz2 + ((size_t)b * MPTS + c0 + j) * 3;
    x2[j] = p[0]; y2[j] = p[1]; z2[j] = p[2]; acc[j] = 0.0f;
  }
  for (int ch = 0; ch < 2; ++ch) {
    __syncthreads();
    for (int n = tid; n < CHUNK; n += BLOCK) {
      int gn = ch * CHUNK + n;
      const float* p = xyz1 + ((size_t)b * NPTS + gn) * 3;
      sm.sP[n] = make_float4(p[0], p[1], p[2], rowscale[b * NPTS + gn]);
    }
    __syncthreads();
    const int nb = wave * 256 + phase;
#pragma unroll
    for (int it = 0; it < 8; ++it) {
      float4 v = sm.sP[nb + it * 32];
#pragma unroll
      for (int j = 0; j < 8; ++j) {
        float dx = x2[j] - v.x, dy = y2[j] - v.y, dz = z2[j] - v.z;
        float d2 = __builtin_fmaf(dx, dx, __builtin_fmaf(dy, dy, dz * dz));
        acc[j] = __builtin_fmaf(__builtin_amdgcn_exp2f(L2C * d2), v.w, acc[j]);
      }
    }
  }
#pragma unroll
  for (int j = 0; j < 8; ++j) {
    acc[j] += __shfl_xor(acc[j], 2, 64);
    acc[j] += __shfl_xor(acc[j], 4, 64);
    acc[j] += __shfl_xor(acc[j], 8, 64);
    acc[j] += __shfl_xor(acc[j], 16, 64);
    acc[j] += __shfl_xor(acc[j], 32, 64);
  }
  if (lane < 2) {
#pragma unroll
    for (int j = 0; j < 8; ++j) sm.sRedS[(rg * 8 + j) * 4 + wave] = acc[j];
  }
  __syncthreads();
  if (tid < ROWS) {
    float t1 = sm.sRedS[tid * 4] + sm.sRedS[tid * 4 + 1] + sm.sRedS[tid * 4 + 2] +
               sm.sRedS[tid * 4 + 3];
    size_t idx = (size_t)b * MPTS + t0 + tid;
    float rr = (l == 0) ? 1.0f : remainR[idx];
    float colsum = rr * t1;
    float cs = fminf(rr / (colsum + 1e-9f), 1.0f);
    colcoef[idx] = rr * cs;
    remainR[idx] = fmaxf(rr - colsum * cs, 0.0f);
  }
}

// ---------------------------------------------------------------------------
// CA(l): row pass: cost(l) + remainL update + rowscale(l+1), sharing d2.
__device__ __forceinline__ void dev_CA(int l, int tile, int tid,
                                       const float* xyz1, const float* xyz2,
                                       float* rowscale, float* remainL,
                                       const float* remainR,
                                       const float* colcoef, float* out,
                                       SmemT& sm) {
  const int b = tile >> 7;
  const int t0 = (tile & 127) * ROWS;
  const int wave = tid >> 6, lane = tid & 63;
  const int phase = lane >> 2, rg = lane & 3;
  const int r0 = t0 + rg * 4;
  const float L2C = -__builtin_amdgcn_exp2f((float)(14 - 2 * l)) * LOG2E;
  const float L2A = (l == 8) ? 0.0f
                             : -__builtin_amdgcn_exp2f((float)(12 - 2 * l)) * LOG2E;
  float x1[4], y1[4], z1[4];
#pragma unroll
  for (int j = 0; j < 4; ++j) {
    const float* p = xyz1 + ((size_t)b * NPTS + r0 + j) * 3;
    x1[j] = p[0]; y1[j] = p[1]; z1[j] = p[2];
  }
  float accS[4] = {0.f, 0.f, 0.f, 0.f};
  float accC[4] = {0.f, 0.f, 0.f, 0.f};
  float accR[4] = {0.f, 0.f, 0.f, 0.f};
  for (int ch = 0; ch < 2; ++ch) {
    __syncthreads();
    for (int m = tid; m < CHUNK; m += BLOCK) {
      size_t idx = (size_t)b * MPTS + ch * CHUNK + m;
      const float* p = xyz2 + idx * 3;
      __half2 h = __halves2half2(__float2half_rn(colcoef[idx]),
                                 __float2half_rn(remainR[idx]));
      sm.sP[m] = make_float4(p[0], p[1], p[2], __builtin_bit_cast(float, h));
    }
    __syncthreads();
    const int mb = wave * 256 + phase;
#pragma unroll
    for (int it = 0; it < 16; ++it) {
      float4 v = sm.sP[mb + it * 16];
      __half2 h = __builtin_bit_cast(__half2, v.w);
      float cc = __low2float(h);
      float rr = __high2float(h);
#pragma unroll
      for (int j = 0; j < 4; ++j) {
        float dx = x1[j] - v.x, dy = y1[j] - v.y, dz = z1[j] - v.z;
        float d2 = __builtin_fmaf(dx, dx, __builtin_fmaf(dy, dy, dz * dz));
        float sq = __builtin_sqrtf(d2);
        float e1 = __builtin_amdgcn_exp2f(L2C * d2);
        float e2 = __builtin_amdgcn_exp2f(L2A * d2);
        float t = e1 * cc;
        accS[j] += t;
        accC[j] = __builtin_fmaf(t, sq, accC[j]);
        accR[j] = __builtin_fmaf(e2, rr, accR[j]);
      }
    }
  }
#pragma unroll
  for (int j = 0; j < 4; ++j) {
    accS[j] += __shfl_xor(accS[j], 4, 64);
    accS[j] += __shfl_xor(accS[j], 8, 64);
    accS[j] += __shfl_xor(accS[j], 16, 64);
    accS[j] += __shfl_xor(accS[j], 32, 64);
    accC[j] += __shfl_xor(accC[j], 4, 64);
    accC[j] += __shfl_xor(accC[j], 8, 64);
    accC[j] += __shfl_xor(accC[j], 16, 64);
    accC[j] += __shfl_xor(accC[j], 32, 64);
    accR[j] += __shfl_xor(accR[j], 4, 64);
    accR[j] += __shfl_xor(accR[j], 8, 64);
    accR[j] += __shfl_xor(accR[j], 16, 64);
    accR[j] += __shfl_xor(accR[j], 32, 64);
  }
  if (lane < 4) {
#pragma unroll
    for (int j = 0; j < 4; ++j) {
      sm.sRedS[(rg * 4 + j) * 4 + wave] = accS[j];
      sm.sRedC[(rg * 4 + j) * 4 + wave] = accC[j];
      sm.sRedR[(rg * 4 + j) * 4 + wave] = accR[j];
    }
  }
  __syncthreads();
  if (tid < ROWS) {
    float S2 = sm.sRedS[tid * 4] + sm.sRedS[tid * 4 + 1] + sm.sRedS[tid * 4 + 2] +
               sm.sRedS[tid * 4 + 3];
    float C = sm.sRedC[tid * 4] + sm.sRedC[tid * 4 + 1] + sm.sRedC[tid * 4 + 2] +
              sm.sRedC[tid * 4 + 3];
    float R = sm.sRedR[tid * 4] + sm.sRedR[tid * 4 + 1] + sm.sRedR[tid * 4 + 2] +
              sm.sRedR[tid * 4 + 3];
    size_t idx = (size_t)b * NPTS + t0 + tid;
    float rs = rowscale[idx];
    float rl = (l == 0) ? 1.0f : remainL[idx];
    float rlN = fmaxf(rl - rs * S2, 0.0f);
    remainL[idx] = rlN;
    rowscale[idx] = rlN / (R + 1e-9f);
    sm.sCost[tid] = rs * C;
  }
  __syncthreads();
  if (tid == 0) {
    float t = 0.0f;
#pragma unroll
    for (int i = 0; i < ROWS; ++i) t += sm.sCost[i];
    atomicAdd(out + b, t);
  }
}

// ---------------------------------------------------------------------------
// B9 (lvl=0): t1 = sum_n rs[n]; colcoef = rr*min(rr/(rr*t1+1e-9),1)
__device__ __forceinline__ void dev_B9(int tile, int tid,
                                       const float* rowscale,
                                       const float* remainR, float* colcoef,
                                       SmemT& sm) {
  const int b = tile >> 7;
  const int t0 = (tile & 127) * ROWS;
  const int wave = tid >> 6, lane = tid & 63;
  __syncthreads();
  float s = 0.0f;
#pragma unroll
  for (int k = 0; k < NPTS / BLOCK; ++k)
    s += rowscale[(size_t)b * NPTS + tid + k * BLOCK];
  s += __shfl_xor(s, 1, 64);
  s += __shfl_xor(s, 2, 64);
  s += __shfl_xor(s, 4, 64);
  s += __shfl_xor(s, 8, 64);
  s += __shfl_xor(s, 16, 64);
  s += __shfl_xor(s, 32, 64);
  if (lane == 0) sm.sW[wave] = s;
  __syncthreads();
  float t1 = sm.sW[0] + sm.sW[1] + sm.sW[2] + sm.sW[3];
  if (tid < ROWS) {
    size_t idx = (size_t)b * MPTS + t0 + tid;
    float rr = remainR[idx];
    float colsum = rr * t1;
    float cs = fminf(rr / (colsum + 1e-9f), 1.0f);
    colcoef[idx] = rr * cs;
  }
}

// ---------------------------------------------------------------------------
// C9 (lvl=0): cost[b] += rs[n] * sum_m cc[m]*sqrt(d2)
__device__ __forceinline__ void dev_C9(int tile, int tid, const float* xyz1,
                                       const float* xyz2,
                                       const float* rowscale,
                                       const float* colcoef, float* out,
                                       SmemT& sm) {
  const int b = tile >> 7;
  const int t0 = (tile & 127) * ROWS;
  const int wave = tid >> 6, lane = tid & 63;
  const int phase = lane >> 1, rg = lane & 1;
  const int r0 = t0 + rg * 8;
  float x1[8], y1[8], z1[8], acc[8];
#pragma unroll
  for (int j = 0; j < 8; ++j) {
    const float* p = xyz1 + ((size_t)b * NPTS + r0 + j) * 3;
    x1[j] = p[0]; y1[j] = p[1]; z1[j] = p[2]; acc[j] = 0.0f;
  }
  for (int ch = 0; ch < 2; ++ch) {
    __syncthreads();
    for (int m = tid; m < CHUNK; m += BLOCK) {
      size_t idx = (size_t)b * MPTS + ch * CHUNK + m;
      const float* p = xyz2 + idx * 3;
      sm.sP[m] = make_float4(p[0], p[1], p[2], colcoef[idx]);
    }
    __syncthreads();
    const int mb = wave * 256 + phase;
#pragma unroll
    for (int it = 0; it < 8; ++it) {
      float4 v = sm.sP[mb + it * 32];
#pragma unroll
      for (int j = 0; j < 8; ++j) {
        float dx = x1[j] - v.x, dy = y1[j] - v.y, dz = z1[j] - v.z;
        float d2 = __builtin_fmaf(dx, dx, __builtin_fmaf(dy, dy, dz * dz));
        acc[j] = __builtin_fmaf(__builtin_sqrtf(d2), v.w, acc[j]);
      }
    }
  }
#pragma unroll
  for (int j = 0; j < 8; ++j) {
    acc[j] += __shfl_xor(acc[j], 2, 64);
    acc[j] += __shfl_xor(acc[j], 4, 64);
    acc[j] += __shfl_xor(acc[j], 8, 64);
    acc[j] += __shfl_xor(acc[j], 16, 64);
    acc[j] += __shfl_xor(acc[j], 32, 64);
  }
  if (lane < 2) {
#pragma unroll
    for (int j = 0; j < 8; ++j) sm.sRedS[(rg * 8 + j) * 4 + wave] = acc[j];
  }
  __syncthreads();
  if (tid < ROWS) {
    float C = sm.sRedS[tid * 4] + sm.sRedS[tid * 4 + 1] + sm.sRedS[tid * 4 + 2] +
              sm.sRedS[tid * 4 + 3];
    sm.sCost[tid] = rowscale[(size_t)b * NPTS + t0 + tid] * C;
  }
  __syncthreads();
  if (tid == 0) {
    float t = 0.0f;
#pragma unroll
    for (int i = 0; i < ROWS; ++i) t += sm.sCost[i];
    atomicAdd(out + b, t);
  }
}

// ---------------------------------------------------------------------------
// Fused cooperative kernel: persistent tiles, 20 grid syncs.
__global__ __launch_bounds__(BLOCK, 4) void emd_fused_kernel(
    const float* __restrict__ xyz1, const float* __restrict__ xyz2,
    float* __restrict__ remainL, float* __restrict__ remainR,
    float* __restrict__ rowscale, float* __restrict__ colcoef,
    float* __restrict__ out) {
  cg::grid_group grid = cg::this_grid();
  __shared__ SmemT sm;
  const int tid = threadIdx.x;
  const int nb = gridDim.x;
  if (blockIdx.x == 0 && tid < BATCH) out[tid] = 0.0f;
  for (int t = blockIdx.x; t < NTILE; t += nb)
    dev_A0(t, tid, xyz1, xyz2, rowscale, sm);
  grid.sync();
  for (int l = 0; l < 9; ++l) {
    for (int t = blockIdx.x; t < NTILE; t += nb)
      dev_B(l, t, tid, xyz1, xyz2, rowscale, remainR, colcoef, sm);
    grid.sync();
    for (int t = blockIdx.x; t < NTILE; t += nb)
      dev_CA(l, t, tid, xyz1, xyz2, rowscale, remainL, remainR, colcoef, out, sm);
    grid.sync();
  }
  for (int t = blockIdx.x; t < NTILE; t += nb)
    dev_B9(t, tid, rowscale, remainR, colcoef, sm);
  grid.sync();
  for (int t = blockIdx.x; t < NTILE; t += nb)
    dev_C9(t, tid, xyz1, xyz2, rowscale, colcoef, out, sm);
}

// ---------------------------------------------------------------------------
// Non-cooperative fallback wrappers (one tile per block, grid = NTILE).
__global__ __launch_bounds__(BLOCK, 4) void k_A0(const float* xyz1,
                                                 const float* xyz2,
                                                 float* rowscale, float* out) {
  __shared__ SmemT sm;
  if (blockIdx.x == 0 && threadIdx.x < BATCH) out[threadIdx.x] = 0.0f;
  dev_A0(blockIdx.x, threadIdx.x, xyz1, xyz2, rowscale, sm);
}
__global__ __launch_bounds__(BLOCK, 4) void k_B(const float* xyz1,
                                                const float* xyz2,
                                                const float* rowscale,
                                                float* remainR, float* colcoef,
                                                int l) {
  __shared__ SmemT sm;
  dev_B(l, blockIdx.x, threadIdx.x, xyz1, xyz2, rowscale, remainR, colcoef, sm);
}
__global__ __launch_bounds__(BLOCK, 4) void k_CA(const float* xyz1,
                                                 const float* xyz2,
                                                 float* rowscale, float* remainL,
                                                 const float* remainR,
                                                 const float* colcoef,
                                                 float* out, int l) {
  __shared__ SmemT sm;
  dev_CA(l, blockIdx.x, threadIdx.x, xyz1, xyz2, rowscale, remainL, remainR,
         colcoef, out, sm);
}
__global__ __launch_bounds__(BLOCK, 4) void k_B9(const float* rowscale,
                                                 const float* remainR,
                                                 float* colcoef) {
  __shared__ SmemT sm;
  dev_B9(blockIdx.x, threadIdx.x, rowscale, remainR, colcoef, sm);
}
__global__ __launch_bounds__(BLOCK, 4) void k_C9(const float* xyz1,
                                                 const float* xyz2,
                                                 const float* rowscale,
                                                 const float* colcoef,
                                                 float* out) {
  __shared__ SmemT sm;
  dev_C9(blockIdx.x, threadIdx.x, xyz1, xyz2, rowscale, colcoef, out, sm);
}

// ---------------------------------------------------------------------------
extern "C" void kernel_launch(void* const* d_in, const int* in_sizes, int n_in,
                              void* d_out, int out_size, void* d_ws, size_t ws_size,
                              hipStream_t stream) {
  const float* xyz1 = (const float*)d_in[0];
  const float* xyz2 = (const float*)d_in[1];
  float* out = (float*)d_out;
  float* ws = (float*)d_ws;

  float* remainL  = ws;                                   // B*N
  float* remainR  = ws + BATCH * NPTS;                    // B*M
  float* rowscale = ws + BATCH * NPTS + BATCH * MPTS;     // B*N
  float* colcoef  = ws + 2 * BATCH * NPTS + BATCH * MPTS; // B*M

  // Host-side, capture-safe queries (deterministic every call).
  int dev = 0;
  hipGetDevice(&dev);
  int coop = 0;
  hipDeviceGetAttribute(&coop, hipDeviceAttributeCooperativeLaunch, dev);
  int nCU = 0;
  hipDeviceGetAttribute(&nCU, hipDeviceAttributeMultiprocessorCount, dev);
  int maxB = 0;
  hipOccupancyMaxActiveBlocksPerMultiprocessor(&maxB, emd_fused_kernel, BLOCK, 0);

  if (coop && maxB > 0 && nCU > 0) {
    int gridN = maxB * nCU;
    if (gridN > NTILE) gridN = NTILE;
    void* args[] = {(void*)&xyz1, (void*)&xyz2, (void*)&remainL,
                    (void*)&remainR, (void*)&rowscale, (void*)&colcoef,
                    (void*)&out};
    hipLaunchCooperativeKernel((void*)emd_fused_kernel, dim3(gridN),
                               dim3(BLOCK), args, 0, stream);
  } else {
    dim3 grid(NTILE);
    k_A0<<<grid, BLOCK, 0, stream>>>(xyz1, xyz2, rowscale, out);
    for (int l = 0; l < 9; ++l) {
      k_B<<<grid, BLOCK, 0, stream>>>(xyz1, xyz2, rowscale, remainR, colcoef, l);
      k_CA<<<grid, BLOCK, 0, stream>>>(xyz1, xyz2, rowscale, remainL, remainR,
                                       colcoef, out, l);
    }
    k_B9<<<grid, BLOCK, 0, stream>>>(rowscale, remainR, colcoef);
    k_C9<<<grid, BLOCK, 0, stream>>>(xyz1, xyz2, rowscale, colcoef, out);
  }
}

// Round 6
// 458.222 us; speedup vs baseline: 3.6610x; 3.6610x over previous
//
#include <hip/hip_runtime.h>
#include <hip/hip_fp16.h>

// EMD approx-match (auction) + match_cost, fused so the [B,N,M] match matrix
// is never materialized. O(B*N) state in d_ws: remainL, remainR, rowscale,
// colcoef. 21 kernels: A0, {B(l), CA(l)} l=0..8, B9sp, C9sp.
//
// R6: transcendental elimination. Fit of R1-R3 timings shows v_exp/v_sqrt
// serialize the SIMD at ~64-97 cyc/wave64 (~30-50x a VALU op) and are the
// real bottleneck (passes ~27us vs ~5us VALU model; 4x TLP bought only
// 1.27x). All exp/sqrt replaced by pure-VALU sequences:
//   exp2: rndne split + deg-4 Taylor on [-.5,.5] + v_ldexp  (8 VALU, ~4e-5)
//   sqrt: rsqrt bit-hack + 2 Newton + mul                   (10 VALU, ~1e-5)
//   CA:   e1 = exp(4*lvlA*d2) = (e2^2)^2  -- one exp2 per pair, not two
// (R5 post-mortem: cooperative grid.sync costs ~60us each on gfx950 due to
// cross-XCD cache flush + spin traffic -- multi-kernel is the right shape.)

#define BATCH 8
#define NPTS 2048
#define MPTS 2048
#define BLOCK 256
#define ROWS 16
#define LOG2E 1.44269504088896340736f

// Pure-VALU 2^x. x <= 0 here; |x| up to ~5.3e6. ldexp handles underflow -> 0.
__device__ __forceinline__ float fast_exp2(float x) {
  float rn = __builtin_rintf(x);        // v_rndne_f32
  float g = x - rn;                     // g in [-0.5, 0.5]
  float p = __builtin_fmaf(
      g,
      __builtin_fmaf(
          g,
          __builtin_fmaf(g,
                         __builtin_fmaf(g, 0.009618129107628477f,
                                        0.05550410866482158f),
                         0.2402265069591007f),
          0.6931471805599453f),
      1.0f);
  return ldexpf(p, (int)rn);            // v_cvt_i32 + v_ldexp_f32
}

// Pure-VALU sqrt(a), a >= 0. Bit-hack rsqrt seed + 2 Newton; a=0 -> 0.
__device__ __forceinline__ float fast_sqrt(float a) {
  int i = 0x5f3759df - (__builtin_bit_cast(int, a) >> 1);
  float y = __builtin_bit_cast(float, i);
  float h = 0.5f * a;
  y = y * __builtin_fmaf(-h * y, y, 1.5f);
  y = y * __builtin_fmaf(-h * y, y, 1.5f);
  return a * y;
}

// ---------------------------------------------------------------------------
// A0: rowscale[b,n] = 1/(sum_m exp(lvl0*d2) + 1e-9). Also zeroes out[].
__global__ __launch_bounds__(BLOCK, 4) void emd_A0_kernel(
    const float* __restrict__ xyz1, const float* __restrict__ xyz2,
    float* __restrict__ rowscale, float* __restrict__ out) {
  __shared__ float4 sP[MPTS];
  __shared__ float sRed[ROWS * 4];

  const int tid = threadIdx.x;
  const int bid = blockIdx.x;
  const int b = bid >> 7;
  const int t0 = (bid & 127) * ROWS;
  if (bid == 0 && tid < BATCH) out[tid] = 0.0f;

  for (int m = tid; m < MPTS; m += BLOCK) {
    const float* p = xyz2 + ((size_t)b * MPTS + m) * 3;
    sP[m] = make_float4(p[0], p[1], p[2], 0.0f);
  }
  __syncthreads();

  const int wave = tid >> 6, lane = tid & 63;
  const int phase = lane >> 1, rg = lane & 1;
  const int r0 = t0 + rg * 8;
  const float L2 = -16384.0f * LOG2E;
  float x1[8], y1[8], z1[8], acc[8];
#pragma unroll
  for (int j = 0; j < 8; ++j) {
    const float* p = xyz1 + ((size_t)b * NPTS + r0 + j) * 3;
    x1[j] = p[0]; y1[j] = p[1]; z1[j] = p[2]; acc[j] = 0.0f;
  }
  const int mb = wave * 512 + phase;
#pragma unroll 2
  for (int it = 0; it < 16; ++it) {
    float4 v = sP[mb + it * 32];
#pragma unroll
    for (int j = 0; j < 8; ++j) {
      float dx = x1[j] - v.x, dy = y1[j] - v.y, dz = z1[j] - v.z;
      float d2 = __builtin_fmaf(dx, dx, __builtin_fmaf(dy, dy, dz * dz));
      acc[j] += fast_exp2(L2 * d2);
    }
  }
#pragma unroll
  for (int j = 0; j < 8; ++j) {
    acc[j] += __shfl_xor(acc[j], 2, 64);
    acc[j] += __shfl_xor(acc[j], 4, 64);
    acc[j] += __shfl_xor(acc[j], 8, 64);
    acc[j] += __shfl_xor(acc[j], 16, 64);
    acc[j] += __shfl_xor(acc[j], 32, 64);
  }
  if (lane < 2) {
#pragma unroll
    for (int j = 0; j < 8; ++j) sRed[(rg * 8 + j) * 4 + wave] = acc[j];
  }
  __syncthreads();
  if (tid < ROWS) {
    float s = sRed[tid * 4] + sRed[tid * 4 + 1] + sRed[tid * 4 + 2] +
              sRed[tid * 4 + 3];
    rowscale[(size_t)b * NPTS + t0 + tid] = 1.0f / (s + 1e-9f);
  }
}

// ---------------------------------------------------------------------------
// B(l): col pass. t1 = sum_n exp(lvl*d2)*rs[n]; colsum = rr*t1;
// cs = min(rr/(colsum+1e-9),1); colcoef = rr*cs; remainR = max(rr-colsum*cs,0)
template <bool FIRST>
__global__ __launch_bounds__(BLOCK, 4) void emd_B_kernel(
    const float* __restrict__ xyz1, const float* __restrict__ xyz2,
    const float* __restrict__ rowscale, float* __restrict__ remainR,
    float* __restrict__ colcoef, float L2C) {
  __shared__ float4 sP[NPTS];   // (x1,y1,z1, rowscale)
  __shared__ float sRed[ROWS * 4];

  const int tid = threadIdx.x;
  const int bid = blockIdx.x;
  const int b = bid >> 7;
  const int t0 = (bid & 127) * ROWS;

  for (int n = tid; n < NPTS; n += BLOCK) {
    const float* p = xyz1 + ((size_t)b * NPTS + n) * 3;
    sP[n] = make_float4(p[0], p[1], p[2], rowscale[b * NPTS + n]);
  }
  __syncthreads();

  const int wave = tid >> 6, lane = tid & 63;
  const int phase = lane >> 1, rg = lane & 1;
  const int c0 = t0 + rg * 8;
  float x2[8], y2[8], z2[8], acc[8];
#pragma unroll
  for (int j = 0; j < 8; ++j) {
    const float* p = xyz2 + ((size_t)b * MPTS + c0 + j) * 3;
    x2[j] = p[0]; y2[j] = p[1]; z2[j] = p[2]; acc[j] = 0.0f;
  }
  const int nb = wave * 512 + phase;
#pragma unroll 2
  for (int it = 0; it < 16; ++it) {
    float4 v = sP[nb + it * 32];
#pragma unroll
    for (int j = 0; j < 8; ++j) {
      float dx = x2[j] - v.x, dy = y2[j] - v.y, dz = z2[j] - v.z;
      float d2 = __builtin_fmaf(dx, dx, __builtin_fmaf(dy, dy, dz * dz));
      acc[j] = __builtin_fmaf(fast_exp2(L2C * d2), v.w, acc[j]);
    }
  }
#pragma unroll
  for (int j = 0; j < 8; ++j) {
    acc[j] += __shfl_xor(acc[j], 2, 64);
    acc[j] += __shfl_xor(acc[j], 4, 64);
    acc[j] += __shfl_xor(acc[j], 8, 64);
    acc[j] += __shfl_xor(acc[j], 16, 64);
    acc[j] += __shfl_xor(acc[j], 32, 64);
  }
  if (lane < 2) {
#pragma unroll
    for (int j = 0; j < 8; ++j) sRed[(rg * 8 + j) * 4 + wave] = acc[j];
  }
  __syncthreads();
  if (tid < ROWS) {
    float t1 = sRed[tid * 4] + sRed[tid * 4 + 1] + sRed[tid * 4 + 2] +
               sRed[tid * 4 + 3];
    size_t idx = (size_t)b * MPTS + t0 + tid;
    float rr = FIRST ? 1.0f : remainR[idx];
    float colsum = rr * t1;
    float cs = fminf(rr / (colsum + 1e-9f), 1.0f);
    colcoef[idx] = rr * cs;
    remainR[idx] = fmaxf(rr - colsum * cs, 0.0f);
  }
}

// ---------------------------------------------------------------------------
// CA(l): row pass: cost(l) + remainL update + rowscale(l+1).
// e2 = exp(lvlA*d2) (ONE exp); e1 = exp(lvlC*d2) = e2^4 since lvlC = 4*lvlA.
// LAST (l==8): lvlA = 0 -> e2 = 1, e1 = exp2(L2C*d2) directly.
template <bool FIRST, bool LAST>
__global__ __launch_bounds__(BLOCK, 4) void emd_CA_kernel(
    const float* __restrict__ xyz1, const float* __restrict__ xyz2,
    float* __restrict__ rowscale, float* __restrict__ remainL,
    const float* __restrict__ remainR, const float* __restrict__ colcoef,
    float* __restrict__ out, float L2C, float L2A) {
  __shared__ float4 sP[MPTS];   // (x2,y2,z2, half2(cc, rr))
  __shared__ float sRedS[ROWS * 4];
  __shared__ float sRedC[ROWS * 4];
  __shared__ float sRedR[ROWS * 4];
  __shared__ float sCost[ROWS];

  const int tid = threadIdx.x;
  const int bid = blockIdx.x;
  const int b = bid >> 7;
  const int t0 = (bid & 127) * ROWS;

  for (int m = tid; m < MPTS; m += BLOCK) {
    size_t idx = (size_t)b * MPTS + m;
    const float* p = xyz2 + idx * 3;
    __half2 h = __halves2half2(__float2half_rn(colcoef[idx]),
                               __float2half_rn(remainR[idx]));
    sP[m] = make_float4(p[0], p[1], p[2], __builtin_bit_cast(float, h));
  }
  __syncthreads();

  const int wave = tid >> 6, lane = tid & 63;
  const int phase = lane >> 2, rg = lane & 3;
  const int r0 = t0 + rg * 4;
  float x1[4], y1[4], z1[4];
#pragma unroll
  for (int j = 0; j < 4; ++j) {
    const float* p = xyz1 + ((size_t)b * NPTS + r0 + j) * 3;
    x1[j] = p[0]; y1[j] = p[1]; z1[j] = p[2];
  }
  float accS[4] = {0.f, 0.f, 0.f, 0.f};
  float accC[4] = {0.f, 0.f, 0.f, 0.f};
  float accR[4] = {0.f, 0.f, 0.f, 0.f};
  const int mb = wave * 512 + phase;
#pragma unroll 4
  for (int it = 0; it < 32; ++it) {
    float4 v = sP[mb + it * 16];
    __half2 h = __builtin_bit_cast(__half2, v.w);
    float cc = __low2float(h);
    float rr = __high2float(h);
#pragma unroll
    for (int j = 0; j < 4; ++j) {
      float dx = x1[j] - v.x, dy = y1[j] - v.y, dz = z1[j] - v.z;
      float d2 = __builtin_fmaf(dx, dx, __builtin_fmaf(dy, dy, dz * dz));
      float sq = fast_sqrt(d2);
      float e1, e2;
      if (LAST) {
        e2 = 1.0f;
        e1 = fast_exp2(L2C * d2);
      } else {
        e2 = fast_exp2(L2A * d2);
        float e2s = e2 * e2;
        e1 = e2s * e2s;             // exp(4*lvlA*d2) exactly matches lvlC
      }
      float t = e1 * cc;
      accS[j] += t;
      accC[j] = __builtin_fmaf(t, sq, accC[j]);
      accR[j] = __builtin_fmaf(e2, rr, accR[j]);
    }
  }
#pragma unroll
  for (int j = 0; j < 4; ++j) {
    accS[j] += __shfl_xor(accS[j], 4, 64);
    accS[j] += __shfl_xor(accS[j], 8, 64);
    accS[j] += __shfl_xor(accS[j], 16, 64);
    accS[j] += __shfl_xor(accS[j], 32, 64);
    accC[j] += __shfl_xor(accC[j], 4, 64);
    accC[j] += __shfl_xor(accC[j], 8, 64);
    accC[j] += __shfl_xor(accC[j], 16, 64);
    accC[j] += __shfl_xor(accC[j], 32, 64);
    accR[j] += __shfl_xor(accR[j], 4, 64);
    accR[j] += __shfl_xor(accR[j], 8, 64);
    accR[j] += __shfl_xor(accR[j], 16, 64);
    accR[j] += __shfl_xor(accR[j], 32, 64);
  }
  if (lane < 4) {
#pragma unroll
    for (int j = 0; j < 4; ++j) {
      sRedS[(rg * 4 + j) * 4 + wave] = accS[j];
      sRedC[(rg * 4 + j) * 4 + wave] = accC[j];
      sRedR[(rg * 4 + j) * 4 + wave] = accR[j];
    }
  }
  __syncthreads();
  if (tid < ROWS) {
    float S2 = sRedS[tid * 4] + sRedS[tid * 4 + 1] + sRedS[tid * 4 + 2] +
               sRedS[tid * 4 + 3];
    float C = sRedC[tid * 4] + sRedC[tid * 4 + 1] + sRedC[tid * 4 + 2] +
              sRedC[tid * 4 + 3];
    float R = sRedR[tid * 4] + sRedR[tid * 4 + 1] + sRedR[tid * 4 + 2] +
              sRedR[tid * 4 + 3];
    size_t idx = (size_t)b * NPTS + t0 + tid;
    float rs = rowscale[idx];
    float rl = FIRST ? 1.0f : remainL[idx];
    float rlN = fmaxf(rl - rs * S2, 0.0f);
    remainL[idx] = rlN;
    rowscale[idx] = rlN / (R + 1e-9f);  // next level's rowscale
    sCost[tid] = rs * C;
  }
  __syncthreads();
  if (tid == 0) {
    float t = 0.0f;
#pragma unroll
    for (int i = 0; i < ROWS; ++i) t += sCost[i];
    atomicAdd(out + b, t);
  }
}

// ---------------------------------------------------------------------------
// B9 (lvl=0): t1 = sum_n rs[n]; colcoef = rr*min(rr/(rr*t1+1e-9),1)
__global__ __launch_bounds__(BLOCK) void emd_B9_kernel(
    const float* __restrict__ rowscale, const float* __restrict__ remainR,
    float* __restrict__ colcoef) {
  __shared__ float sW[4];
  const int tid = threadIdx.x;
  const int b = blockIdx.x;
  float s = 0.0f;
#pragma unroll
  for (int k = 0; k < NPTS / BLOCK; ++k)
    s += rowscale[(size_t)b * NPTS + tid + k * BLOCK];
  s += __shfl_xor(s, 1, 64);  s += __shfl_xor(s, 2, 64);
  s += __shfl_xor(s, 4, 64);  s += __shfl_xor(s, 8, 64);
  s += __shfl_xor(s, 16, 64); s += __shfl_xor(s, 32, 64);
  if ((tid & 63) == 0) sW[tid >> 6] = s;
  __syncthreads();
  float t1 = sW[0] + sW[1] + sW[2] + sW[3];
  for (int m = tid; m < MPTS; m += BLOCK) {
    size_t idx = (size_t)b * MPTS + m;
    float rr = remainR[idx];
    float colsum = rr * t1;
    float cs = fminf(rr / (colsum + 1e-9f), 1.0f);
    colcoef[idx] = rr * cs;
  }
}

// ---------------------------------------------------------------------------
// C9 (lvl=0): cost[b] += rs[n] * sum_m cc[m]*sqrt(d2)
__global__ __launch_bounds__(BLOCK, 4) void emd_C9_kernel(
    const float* __restrict__ xyz1, const float* __restrict__ xyz2,
    const float* __restrict__ rowscale, const float* __restrict__ colcoef,
    float* __restrict__ out) {
  __shared__ float4 sP[MPTS];   // (x2,y2,z2, colcoef)
  __shared__ float sRed[ROWS * 4];
  __shared__ float sCost[ROWS];

  const int tid = threadIdx.x;
  const int bid = blockIdx.x;
  const int b = bid >> 7;
  const int t0 = (bid & 127) * ROWS;

  for (int m = tid; m < MPTS; m += BLOCK) {
    size_t idx = (size_t)b * MPTS + m;
    const float* p = xyz2 + idx * 3;
    sP[m] = make_float4(p[0], p[1], p[2], colcoef[idx]);
  }
  __syncthreads();

  const int wave = tid >> 6, lane = tid & 63;
  const int phase = lane >> 1, rg = lane & 1;
  const int r0 = t0 + rg * 8;
  float x1[8], y1[8], z1[8], acc[8];
#pragma unroll
  for (int j = 0; j < 8; ++j) {
    const float* p = xyz1 + ((size_t)b * NPTS + r0 + j) * 3;
    x1[j] = p[0]; y1[j] = p[1]; z1[j] = p[2]; acc[j] = 0.0f;
  }
  const int mb = wave * 512 + phase;
#pragma unroll 2
  for (int it = 0; it < 16; ++it) {
    float4 v = sP[mb + it * 32];
#pragma unroll
    for (int j = 0; j < 8; ++j) {
      float dx = x1[j] - v.x, dy = y1[j] - v.y, dz = z1[j] - v.z;
      float d2 = __builtin_fmaf(dx, dx, __builtin_fmaf(dy, dy, dz * dz));
      acc[j] = __builtin_fmaf(fast_sqrt(d2), v.w, acc[j]);
    }
  }
#pragma unroll
  for (int j = 0; j < 8; ++j) {
    acc[j] += __shfl_xor(acc[j], 2, 64);
    acc[j] += __shfl_xor(acc[j], 4, 64);
    acc[j] += __shfl_xor(acc[j], 8, 64);
    acc[j] += __shfl_xor(acc[j], 16, 64);
    acc[j] += __shfl_xor(acc[j], 32, 64);
  }
  if (lane < 2) {
#pragma unroll
    for (int j = 0; j < 8; ++j) sRed[(rg * 8 + j) * 4 + wave] = acc[j];
  }
  __syncthreads();
  if (tid < ROWS) {
    float C = sRed[tid * 4] + sRed[tid * 4 + 1] + sRed[tid * 4 + 2] +
              sRed[tid * 4 + 3];
    sCost[tid] = rowscale[(size_t)b * NPTS + t0 + tid] * C;
  }
  __syncthreads();
  if (tid == 0) {
    float t = 0.0f;
#pragma unroll
    for (int i = 0; i < ROWS; ++i) t += sCost[i];
    atomicAdd(out + b, t);
  }
}

// ---------------------------------------------------------------------------
extern "C" void kernel_launch(void* const* d_in, const int* in_sizes, int n_in,
                              void* d_out, int out_size, void* d_ws, size_t ws_size,
                              hipStream_t stream) {
  const float* xyz1 = (const float*)d_in[0];
  const float* xyz2 = (const float*)d_in[1];
  float* out = (float*)d_out;
  float* ws = (float*)d_ws;

  float* remainL  = ws;                                   // B*N
  float* remainR  = ws + BATCH * NPTS;                    // B*M
  float* rowscale = ws + BATCH * NPTS + BATCH * MPTS;     // B*N
  float* colcoef  = ws + 2 * BATCH * NPTS + BATCH * MPTS; // B*M

  // levels[l] = -4^(7-l) for l=0..8 (then 0 handled by specialized kernels)
  const float levels[9] = {-16384.f, -4096.f, -1024.f, -256.f, -64.f,
                           -16.f,    -4.f,    -1.f,    -0.25f};
  dim3 grid(BATCH * (NPTS / ROWS));  // 1024 blocks

  emd_A0_kernel<<<grid, BLOCK, 0, stream>>>(xyz1, xyz2, rowscale, out);

  for (int l = 0; l < 9; ++l) {
    float L2C = levels[l] * LOG2E;
    float L2A = 0.25f * L2C;  // next level = lvl/4 (exact powers of 4)
    if (l == 0) {
      emd_B_kernel<true><<<grid, BLOCK, 0, stream>>>(xyz1, xyz2, rowscale,
                                                     remainR, colcoef, L2C);
      emd_CA_kernel<true, false><<<grid, BLOCK, 0, stream>>>(
          xyz1, xyz2, rowscale, remainL, remainR, colcoef, out, L2C, L2A);
    } else if (l < 8) {
      emd_B_kernel<false><<<grid, BLOCK, 0, stream>>>(xyz1, xyz2, rowscale,
                                                      remainR, colcoef, L2C);
      emd_CA_kernel<false, false><<<grid, BLOCK, 0, stream>>>(
          xyz1, xyz2, rowscale, remainL, remainR, colcoef, out, L2C, L2A);
    } else {
      emd_B_kernel<false><<<grid, BLOCK, 0, stream>>>(xyz1, xyz2, rowscale,
                                                      remainR, colcoef, L2C);
      emd_CA_kernel<false, true><<<grid, BLOCK, 0, stream>>>(
          xyz1, xyz2, rowscale, remainL, remainR, colcoef, out, L2C, 0.0f);
    }
  }
  emd_B9_kernel<<<BATCH, BLOCK, 0, stream>>>(rowscale, remainR, colcoef);
  emd_C9_kernel<<<grid, BLOCK, 0, stream>>>(xyz1, xyz2, rowscale, colcoef, out);
}